// Round 2
// baseline (17608.763 us; speedup 1.0000x reference)
//
#include <hip/hip_runtime.h>
#include <hip/hip_bf16.h>
#include <cmath>

typedef __attribute__((ext_vector_type(8))) short short8;   // 8 bf16 = 4 VGPRs
typedef __attribute__((ext_vector_type(4))) float floatx4;  // MFMA 16x16 accumulator

#define NB   64
#define TS   512
#define DIM  1024
#define HD   1024
#define KTOT 2048
#define GRID_BLOCKS 256
#define ROWSTRIDE ((size_t)TS * HD)   // batch-row stride of x and out (elements)

// ---------------------------------------------------------------------------
// One-time transpose + fp32->bf16: WT[j][k] = bf16( k<1024 ? Wx[k][j] : Wh[k-1024][j] )
// ---------------------------------------------------------------------------
__global__ void build_wt(const float* __restrict__ Wx,
                         const float* __restrict__ Wh,
                         __hip_bfloat16* __restrict__ WT) {
    __shared__ __hip_bfloat16 tile[32][33];
    const int j0 = blockIdx.x * 32;          // 128 j-tiles
    const int k0 = blockIdx.y * 32;          // 64  k-tiles
    const int tx = threadIdx.x & 31;
    const int ty = threadIdx.x >> 5;         // 0..7
    #pragma unroll
    for (int kk = 0; kk < 32; kk += 8) {
        const int k = k0 + ty + kk;
        const float* S = (k < DIM) ? (Wx + (size_t)k * 4096)
                                   : (Wh + (size_t)(k - DIM) * 4096);
        tile[ty + kk][tx] = __float2bfloat16(S[j0 + tx]);
    }
    __syncthreads();
    #pragma unroll
    for (int kk = 0; kk < 32; kk += 8) {
        const int j = j0 + ty + kk;
        WT[(size_t)j * KTOT + k0 + tx] = tile[tx][ty + kk];
    }
}

// ---------------------------------------------------------------------------
// Grid barrier: per-block flags, monotone target. Grid must be co-resident
// (grid == 256 == #CUs, __launch_bounds__(256,1) => >=1 block/CU).
// ---------------------------------------------------------------------------
__device__ inline void grid_barrier(unsigned* flags, unsigned target) {
    __syncthreads();                     // all block work done (drains vmcnt)
    if (threadIdx.x == 0) {
        __threadfence();                 // release: flush this CU's writes
        __hip_atomic_store(flags + blockIdx.x, target,
                           __ATOMIC_RELEASE, __HIP_MEMORY_SCOPE_AGENT);
    }
    if (threadIdx.x < 64) {
        const int l = threadIdx.x;
        for (;;) {
            unsigned a = __hip_atomic_load(flags + l,       __ATOMIC_RELAXED, __HIP_MEMORY_SCOPE_AGENT);
            unsigned b = __hip_atomic_load(flags + 64 + l,  __ATOMIC_RELAXED, __HIP_MEMORY_SCOPE_AGENT);
            unsigned c = __hip_atomic_load(flags + 128 + l, __ATOMIC_RELAXED, __HIP_MEMORY_SCOPE_AGENT);
            unsigned d = __hip_atomic_load(flags + 192 + l, __ATOMIC_RELAXED, __HIP_MEMORY_SCOPE_AGENT);
            int ok = (a >= target) && (b >= target) && (c >= target) && (d >= target);
            if (__all(ok)) break;
            __builtin_amdgcn_s_sleep(1);
        }
        __threadfence();                 // acquire: invalidate stale L1/L2
    }
    __syncthreads();
}

// ---------------------------------------------------------------------------
// Persistent LSTM scan. Block b: ng = b>>6 (16 batch rows), cs = b&63 (16 cols).
// Wave w = gate w (i,f,o,g). mfma_f32_16x16x32_bf16:
//   A lane l: A[m=l&15][k=(l>>4)*8+j]  -> WT row (contig 16B)
//   B lane l: B[k=(l>>4)*8+j][n=l&15]  -> x/h bf16 row (contig 16B)
//   D lane l: D[m=(l>>4)*4+r][n=l&15]  (m = a-col, n = batch)
// ---------------------------------------------------------------------------
__global__ __launch_bounds__(256, 1)
void lstm_scan(const float* __restrict__ x,
               const float* __restrict__ h0,
               const __hip_bfloat16* __restrict__ WT,
               const float* __restrict__ bias,
               float* __restrict__ out,
               __hip_bfloat16* __restrict__ hbuf,   // 2 * 64*1024 bf16
               __hip_bfloat16* __restrict__ xbuf,   // 2 * 64*1024 bf16
               unsigned* __restrict__ flags) {
    __shared__ float lds_g[4][16][17];   // [gate][j_local][n_local]

    const int blk  = blockIdx.x;
    const int ng   = blk >> 6;
    const int cs   = blk & 63;
    const int tid  = threadIdx.x;
    const int wave = tid >> 6;
    const int lane = tid & 63;
    const int n0 = ng * 16;
    const int j0 = cs * 16;

    const int frag_m = lane & 15;
    const int frag_k = (lane >> 4) * 8;

    const __hip_bfloat16* wrow =
        WT + (size_t)(wave * HD + j0 + frag_m) * KTOT + frag_k;
    const int n_l = n0 + frag_m;

    // ---- init: convert h0 and x_0 into bf16 buffers (1 elem / thread) ----
    const int flat = blk * 256 + tid;          // 0..65535 over the grid
    const int pf_n = flat >> 10, pf_d = flat & 1023;
    hbuf[flat] = __float2bfloat16(h0[flat]);   // h0 is (64,1024) contiguous
    xbuf[flat] = __float2bfloat16(x[(size_t)pf_n * ROWSTRIDE + pf_d]);
    grid_barrier(flags, 1);

    // ---- epilogue mapping: tid -> (e_n, e_j), e_j fastest (coalesced) ----
    const int e_j = tid & 15;
    const int e_n = tid >> 4;
    float c_reg = 0.0f;
    const float bi = bias[         j0 + e_j];
    const float bf_ = bias[1 * HD + j0 + e_j];
    const float bo = bias[2 * HD + j0 + e_j];
    const float bg = bias[3 * HD + j0 + e_j];
    float* out_e = out + (size_t)(n0 + e_n) * ROWSTRIDE + j0 + e_j;
    const int hb_idx = (n0 + e_n) * 1024 + j0 + e_j;
    const float* xsrc = x + (size_t)pf_n * ROWSTRIDE + pf_d;

    for (int t = 0; t < TS; ++t) {
        const int par = (t & 1) * 65536;
        const __hip_bfloat16* xb = xbuf + par + n_l * 1024 + frag_k;
        const __hip_bfloat16* hb = hbuf + par + n_l * 1024 + frag_k;
        const __hip_bfloat16* wp = wrow;

        floatx4 acc = {0.f, 0.f, 0.f, 0.f};
        #pragma unroll 8
        for (int kk = 0; kk < DIM; kk += 32) {
            short8 a8 = *(const short8*)(wp + kk);
            short8 b8 = *(const short8*)(xb + kk);
            acc = __builtin_amdgcn_mfma_f32_16x16x32_bf16(a8, b8, acc, 0, 0, 0);
        }
        wp += DIM;
        #pragma unroll 8
        for (int kk = 0; kk < HD; kk += 32) {
            short8 a8 = *(const short8*)(wp + kk);
            short8 b8 = *(const short8*)(hb + kk);
            acc = __builtin_amdgcn_mfma_f32_16x16x32_bf16(a8, b8, acc, 0, 0, 0);
        }

        const int q = lane >> 4;
        #pragma unroll
        for (int r = 0; r < 4; ++r)
            lds_g[wave][q * 4 + r][frag_m] = acc[r];
        __syncthreads();

        const float ai = lds_g[0][e_j][e_n] + bi;
        const float af = lds_g[1][e_j][e_n] + bf_;
        const float ao = lds_g[2][e_j][e_n] + bo;
        const float ag = lds_g[3][e_j][e_n] + bg;
        const float i_g = 1.0f / (1.0f + expf(-ai));
        const float f_g = 1.0f / (1.0f + expf(-af));
        const float o_g = 1.0f / (1.0f + expf(-ao));
        const float g_g = tanhf(ag);
        c_reg = f_g * c_reg + i_g * g_g;
        const float h = o_g * tanhf(c_reg);

        out_e[(size_t)t * HD] = h;                                 // fp32 output
        const int npar = ((t + 1) & 1) * 65536;
        hbuf[npar + hb_idx] = __float2bfloat16(h);                 // bf16 feedback
        if (t + 1 < TS)                                            // convert x_{t+1}
            xbuf[npar + flat] = __float2bfloat16(xsrc[(size_t)(t + 1) * DIM]);

        grid_barrier(flags, (unsigned)(t + 2));
    }
}

// ---------------------------------------------------------------------------
extern "C" void kernel_launch(void* const* d_in, const int* in_sizes, int n_in,
                              void* d_out, int out_size, void* d_ws, size_t ws_size,
                              hipStream_t stream) {
    const float* x  = (const float*)d_in[0];
    const float* h0 = (const float*)d_in[1];
    const float* Wx = (const float*)d_in[2];
    const float* Wh = (const float*)d_in[3];
    const float* b  = (const float*)d_in[4];
    float* out = (float*)d_out;

    char* ws = (char*)d_ws;
    __hip_bfloat16* WT   = (__hip_bfloat16*)ws;                         // 16 MiB
    unsigned*       flags = (unsigned*)(ws + (16u << 20));              // 1 KiB (pad 4K)
    __hip_bfloat16* hbuf = (__hip_bfloat16*)(ws + (16u << 20) + 4096);  // 256 KiB
    __hip_bfloat16* xbuf = hbuf + 2 * 65536;                            // 256 KiB

    hipMemsetAsync(flags, 0, 4096, stream);
    build_wt<<<dim3(128, 64), 256, 0, stream>>>(Wx, Wh, WT);
    lstm_scan<<<GRID_BLOCKS, 256, 0, stream>>>(x, h0, WT, b, out, hbuf, xbuf, flags);
}

// Round 3
// 10906.551 us; speedup vs baseline: 1.6145x; 1.6145x over previous
//
#include <hip/hip_runtime.h>
#include <hip/hip_bf16.h>
#include <cmath>

typedef __attribute__((ext_vector_type(8))) short short8;   // 8 bf16 = 4 VGPRs
typedef __attribute__((ext_vector_type(4))) float floatx4;  // MFMA 16x16 accumulator

#define NB   64
#define TS   512
#define DIM  1024
#define HD   1024
#define KTOT 2048
#define GRID_BLOCKS 256
#define BSTRIDE 2056                  // Bt row stride (bf16 elems): 4112B = 1028dw = 4 banks -> 2-way (free)
#define ROWSTRIDE ((size_t)TS * HD)   // batch-row stride of x and out (elements)

// ---------------------------------------------------------------------------
// One-time transpose + fp32->bf16: WT[j][k] = bf16( k<1024 ? Wx[k][j] : Wh[k-1024][j] )
// ---------------------------------------------------------------------------
__global__ void build_wt(const float* __restrict__ Wx,
                         const float* __restrict__ Wh,
                         __hip_bfloat16* __restrict__ WT) {
    __shared__ __hip_bfloat16 tile[32][33];
    const int j0 = blockIdx.x * 32;
    const int k0 = blockIdx.y * 32;
    const int tx = threadIdx.x & 31;
    const int ty = threadIdx.x >> 5;
    #pragma unroll
    for (int kk = 0; kk < 32; kk += 8) {
        const int k = k0 + ty + kk;
        const float* S = (k < DIM) ? (Wx + (size_t)k * 4096)
                                   : (Wh + (size_t)(k - DIM) * 4096);
        tile[ty + kk][tx] = __float2bfloat16(S[j0 + tx]);
    }
    __syncthreads();
    #pragma unroll
    for (int kk = 0; kk < 32; kk += 8) {
        const int j = j0 + ty + kk;
        WT[(size_t)j * KTOT + k0 + tx] = tile[tx][ty + kk];
    }
}

// ---------------------------------------------------------------------------
// Grid barrier: per-block flags, monotone target. Co-resident: grid==256 CUs,
// __launch_bounds__(256,1) => 1 block/CU.
// ---------------------------------------------------------------------------
__device__ inline void grid_barrier(unsigned* flags, unsigned target) {
    __syncthreads();
    if (threadIdx.x == 0) {
        __threadfence();                 // release: writeback this CU's stores
        __hip_atomic_store(flags + blockIdx.x, target,
                           __ATOMIC_RELEASE, __HIP_MEMORY_SCOPE_AGENT);
    }
    if (threadIdx.x < 64) {
        const int l = threadIdx.x;
        for (;;) {
            unsigned a = __hip_atomic_load(flags + l,       __ATOMIC_RELAXED, __HIP_MEMORY_SCOPE_AGENT);
            unsigned b = __hip_atomic_load(flags + 64 + l,  __ATOMIC_RELAXED, __HIP_MEMORY_SCOPE_AGENT);
            unsigned c = __hip_atomic_load(flags + 128 + l, __ATOMIC_RELAXED, __HIP_MEMORY_SCOPE_AGENT);
            unsigned d = __hip_atomic_load(flags + 192 + l, __ATOMIC_RELAXED, __HIP_MEMORY_SCOPE_AGENT);
            int ok = (a >= target) && (b >= target) && (c >= target) && (d >= target);
            if (__all(ok)) break;
            __builtin_amdgcn_s_sleep(1);
        }
        __threadfence();                 // acquire: invalidate stale cache
    }
    __syncthreads();
}

// ---------------------------------------------------------------------------
// Persistent LSTM scan. Block b: ng=b>>6 (16 batch rows), cs=b&63 (16 cols).
// Wave w = gate w. Weights (A operand) live in 256 VGPRs/wave for the whole
// scan — immune to the fence-induced cache invalidation each step.
// ---------------------------------------------------------------------------
__global__ __launch_bounds__(256, 1)
void lstm_scan(const float* __restrict__ x,
               const float* __restrict__ h0,
               const __hip_bfloat16* __restrict__ WT,
               const float* __restrict__ bias,
               float* __restrict__ out,
               __hip_bfloat16* __restrict__ hbuf,   // 2 * 64*1024 bf16
               unsigned* __restrict__ flags) {
    __shared__ __hip_bfloat16 Bt[16][BSTRIDE];  // [n][k]: k<1024 x, k>=1024 h
    __shared__ float lds_g[4][16][17];          // [gate][j_local][n_local]

    const int blk  = blockIdx.x;
    const int ng   = blk >> 6;
    const int cs   = blk & 63;
    const int tid  = threadIdx.x;
    const int wave = tid >> 6;
    const int lane = tid & 63;
    const int n0 = ng * 16;
    const int j0 = cs * 16;

    const int frag_m = lane & 15;        // A: m (a-col) / B: n (batch row)
    const int frag_k = (lane >> 4) * 8;  // k sub-offset within 32-chunk

    // ---- preload this wave's A fragments: 64 x short8 = 256 VGPRs ----
    const __hip_bfloat16* wrow =
        WT + (size_t)(wave * HD + j0 + frag_m) * KTOT + frag_k;
    short8 wreg[64];
    #pragma unroll
    for (int i = 0; i < 32; ++i)
        wreg[i] = *(const short8*)(wrow + i * 32);
    #pragma unroll
    for (int i = 0; i < 32; ++i)
        wreg[32 + i] = *(const short8*)(wrow + DIM + i * 32);

    // ---- init: h0 -> hbuf[parity 0] (grid-flat, coalesced) ----
    const int flat = blk * 256 + tid;    // 0..65535
    hbuf[flat] = __float2bfloat16(h0[flat]);

    // ---- stage x_0 into Bt x-half (direct fp32 load + convert) ----
    {
        #pragma unroll
        for (int j = 0; j < 8; ++j) {
            const int c = j * 256 + tid;        // 16B chunk id, 0..2047
            const int r = c >> 7;               // row 0..15
            const int col = (c & 127) * 8;      // 0..1016
            const float* xs = x + (size_t)(n0 + r) * ROWSTRIDE + col;
            float4 f0 = *(const float4*)xs;
            float4 f1 = *(const float4*)(xs + 4);
            short8 v;
            v[0] = __bfloat16_as_short(__float2bfloat16(f0.x));
            v[1] = __bfloat16_as_short(__float2bfloat16(f0.y));
            v[2] = __bfloat16_as_short(__float2bfloat16(f0.z));
            v[3] = __bfloat16_as_short(__float2bfloat16(f0.w));
            v[4] = __bfloat16_as_short(__float2bfloat16(f1.x));
            v[5] = __bfloat16_as_short(__float2bfloat16(f1.y));
            v[6] = __bfloat16_as_short(__float2bfloat16(f1.z));
            v[7] = __bfloat16_as_short(__float2bfloat16(f1.w));
            *(short8*)&Bt[r][col] = v;
        }
    }
    grid_barrier(flags, 1);

    // ---- epilogue mapping ----
    const int e_j = tid & 15;
    const int e_n = tid >> 4;
    float c_reg = 0.0f;
    const float bi  = bias[         j0 + e_j];
    const float bf_ = bias[1 * HD + j0 + e_j];
    const float bo  = bias[2 * HD + j0 + e_j];
    const float bg  = bias[3 * HD + j0 + e_j];
    float* out_e = out + (size_t)(n0 + e_n) * ROWSTRIDE + j0 + e_j;
    const int hb_idx = (n0 + e_n) * 1024 + j0 + e_j;
    const int q = lane >> 4;

    for (int t = 0; t < TS; ++t) {
        const int par = (t & 1) * 65536;

        // ---- stage h_{t-1} into Bt h-half (coalesced 16B/lane) ----
        #pragma unroll
        for (int j = 0; j < 8; ++j) {
            const int c = j * 256 + tid;
            const int r = c >> 7;
            const int col = (c & 127) * 8;
            short8 v = *(const short8*)(hbuf + par + (n0 + r) * 1024 + col);
            *(short8*)&Bt[r][1024 + col] = v;
        }
        __syncthreads();

        // ---- MFMA: A from regs, B from LDS ----
        floatx4 acc = {0.f, 0.f, 0.f, 0.f};
        #pragma unroll
        for (int i = 0; i < 32; ++i) {
            short8 b8 = *(const short8*)&Bt[frag_m][i * 32 + frag_k];
            acc = __builtin_amdgcn_mfma_f32_16x16x32_bf16(wreg[i], b8, acc, 0, 0, 0);
        }
        #pragma unroll
        for (int i = 0; i < 32; ++i) {
            short8 b8 = *(const short8*)&Bt[frag_m][1024 + i * 32 + frag_k];
            acc = __builtin_amdgcn_mfma_f32_16x16x32_bf16(wreg[32 + i], b8, acc, 0, 0, 0);
        }

        // ---- gate tile -> lds_g ----
        #pragma unroll
        for (int r = 0; r < 4; ++r)
            lds_g[wave][q * 4 + r][frag_m] = acc[r];
        __syncthreads();

        // ---- gates + state update ----
        const float ai = lds_g[0][e_j][e_n] + bi;
        const float af = lds_g[1][e_j][e_n] + bf_;
        const float ao = lds_g[2][e_j][e_n] + bo;
        const float ag = lds_g[3][e_j][e_n] + bg;
        const float i_g = 1.0f / (1.0f + expf(-ai));
        const float f_g = 1.0f / (1.0f + expf(-af));
        const float o_g = 1.0f / (1.0f + expf(-ao));
        const float g_g = tanhf(ag);
        c_reg = f_g * c_reg + i_g * g_g;
        const float h = o_g * tanhf(c_reg);

        out_e[(size_t)t * HD] = h;                         // fp32 output
        const int npar = ((t + 1) & 1) * 65536;
        hbuf[npar + hb_idx] = __float2bfloat16(h);         // bf16 feedback

        // ---- stage x_{t+1} into Bt x-half (pre-barrier; overlaps wait) ----
        // Safe: all MFMA reads of Bt precede the post-lds_g __syncthreads.
        if (t + 1 < TS) {
            #pragma unroll
            for (int j = 0; j < 8; ++j) {
                const int c = j * 256 + tid;
                const int r = c >> 7;
                const int col = (c & 127) * 8;
                const float* xs = x + (size_t)(n0 + r) * ROWSTRIDE
                                    + (size_t)(t + 1) * DIM + col;
                float4 f0 = *(const float4*)xs;
                float4 f1 = *(const float4*)(xs + 4);
                short8 v;
                v[0] = __bfloat16_as_short(__float2bfloat16(f0.x));
                v[1] = __bfloat16_as_short(__float2bfloat16(f0.y));
                v[2] = __bfloat16_as_short(__float2bfloat16(f0.z));
                v[3] = __bfloat16_as_short(__float2bfloat16(f0.w));
                v[4] = __bfloat16_as_short(__float2bfloat16(f1.x));
                v[5] = __bfloat16_as_short(__float2bfloat16(f1.y));
                v[6] = __bfloat16_as_short(__float2bfloat16(f1.z));
                v[7] = __bfloat16_as_short(__float2bfloat16(f1.w));
                *(short8*)&Bt[r][col] = v;
            }
        }

        grid_barrier(flags, (unsigned)(t + 2));
    }
}

// ---------------------------------------------------------------------------
extern "C" void kernel_launch(void* const* d_in, const int* in_sizes, int n_in,
                              void* d_out, int out_size, void* d_ws, size_t ws_size,
                              hipStream_t stream) {
    const float* x  = (const float*)d_in[0];
    const float* h0 = (const float*)d_in[1];
    const float* Wx = (const float*)d_in[2];
    const float* Wh = (const float*)d_in[3];
    const float* b  = (const float*)d_in[4];
    float* out = (float*)d_out;

    char* ws = (char*)d_ws;
    __hip_bfloat16* WT    = (__hip_bfloat16*)ws;                         // 16 MiB
    unsigned*       flags = (unsigned*)(ws + (16u << 20));               // 1 KiB (4K pad)
    __hip_bfloat16* hbuf  = (__hip_bfloat16*)(ws + (16u << 20) + 4096);  // 256 KiB

    hipMemsetAsync(flags, 0, 4096, stream);
    build_wt<<<dim3(128, 64), 256, 0, stream>>>(Wx, Wh, WT);
    lstm_scan<<<GRID_BLOCKS, 256, 0, stream>>>(x, h0, WT, b, out, hbuf, flags);
}